// Round 7
// baseline (637.518 us; speedup 1.0000x reference)
//
#include <hip/hip_runtime.h>
#include <cstddef>

// Problem constants
#define D_MODEL 768
#define NHEAD   12
#define DHEAD   64
#define RANK    32
#define SEQ     1024
#define BATCH   8
#define BM      8192      // BATCH*SEQ

typedef __attribute__((ext_vector_type(8))) short short8;
typedef __attribute__((ext_vector_type(4))) float floatx4;

__device__ inline ushort f2b(float f) {           // fp32 -> bf16 RNE
  union { float f; unsigned u; } v; v.f = f;
  unsigned r = v.u + 0x7fffu + ((v.u >> 16) & 1u);
  return (ushort)(r >> 16);
}
__device__ inline float b2f(ushort h) {
  union { unsigned u; float f; } v; v.u = ((unsigned)h) << 16;
  return v.f;
}
// pack two fp32 -> bf16x2 dword
__device__ inline unsigned pk2(float a, float b) {
  return ((__float_as_uint(b) + 0x8000u) & 0xffff0000u) |
         ((__float_as_uint(a) + 0x8000u) >> 16);
}
// tanh-form GELU with fast exp (max |err vs erf-GELU| ~1e-3; propagated <1e-3)
__device__ inline float fast_gelu(float x) {
  float z = 0.79788456080286536f * (x + 0.044715f * x * x * x);
  float e = __expf(2.f * z);
  float t = 1.f - 2.f / (e + 1.f);
  return 0.5f * x * (1.f + t);
}

// ---------------------------------------------------------------------------
__global__ __launch_bounds__(256) void f2b_kernel(
    const float* __restrict__ in, ushort* __restrict__ out, int n) {
  int i = (blockIdx.x * 256 + threadIdx.x) * 4;
  if (i >= n) return;
  float4 v = *(const float4*)(in + i);
  ushort4 o;
  o.x = f2b(v.x); o.y = f2b(v.y); o.z = f2b(v.z); o.w = f2b(v.w);
  *(ushort4*)(out + i) = o;
}

// ---------------------------------------------------------------------------
// All three QKV low-rank combines in one launch (grid.y selects q/k/v):
// Wt[y][c=h*64+k][d] = sum_r P[h,d,r] * Vw[h,r,k]
// ---------------------------------------------------------------------------
__global__ __launch_bounds__(256) void combine_qkv_kernel(
    const float* __restrict__ Pq, const float* __restrict__ Vq,
    const float* __restrict__ Pk, const float* __restrict__ Vk,
    const float* __restrict__ Pv, const float* __restrict__ Vv,
    ushort* __restrict__ Wt) {
  int which = blockIdx.y;
  const float* P  = which == 0 ? Pq : (which == 1 ? Pk : Pv);
  const float* Vw = which == 0 ? Vq : (which == 1 ? Vk : Vv);
  ushort* W = Wt + (size_t)which * D_MODEL * D_MODEL;
  int idx = blockIdx.x * 256 + threadIdx.x;
  if (idx >= D_MODEL * NHEAD * DHEAD) return;
  int c = idx / D_MODEL;
  int d = idx - c * D_MODEL;
  int h = c >> 6, k = c & 63;
  const float* p = P + ((size_t)h * D_MODEL + d) * RANK;
  const float* v = Vw + (size_t)h * RANK * DHEAD + k;
  float s = 0.f;
#pragma unroll
  for (int r = 0; r < RANK; r++) s += p[r] * v[(size_t)r * DHEAD];
  W[(size_t)c * D_MODEL + d] = f2b(s);
}

__global__ __launch_bounds__(256) void concat_bias_kernel(
    const float* __restrict__ bq, const float* __restrict__ bk,
    const float* __restrict__ bv, float* __restrict__ out) {
  int i = blockIdx.x * 256 + threadIdx.x;
  if (i >= 2304) return;
  out[i] = (i < 768) ? bq[i] : (i < 1536 ? bk[i - 768] : bv[i - 1536]);
}

// ---------------------------------------------------------------------------
// Wot[n][d] = sum_r Uo[d][r] * Vo[r][n]   (full-rank attn-out weight, bf16,
// transposed layout for the Bt GEMM operand). 768x768, K=384.
// ---------------------------------------------------------------------------
__global__ __launch_bounds__(256) void combine_wo_kernel(
    const float* __restrict__ Uo, const float* __restrict__ Vo,
    ushort* __restrict__ Wot) {
  int idx = blockIdx.x * 256 + threadIdx.x;
  if (idx >= 768 * 768) return;
  int n = idx / 768, d = idx - n * 768;
  const float* up = Uo + (size_t)d * 384;
  const float* vp = Vo + n;
  float s = 0.f;
  for (int r = 0; r < 384; r++) s += up[r] * vp[(size_t)r * 768];
  Wot[idx] = f2b(s);
}

// ---------------------------------------------------------------------------
// Four weight transposes in one launch (block-range decode):
// U1(768,384) V1(384,3072) U2(3072,384) V2(384,768), fp32 -> bf16 transposed.
// ---------------------------------------------------------------------------
__global__ __launch_bounds__(256) void transpose4_kernel(
    const float* __restrict__ U1, const float* __restrict__ V1,
    const float* __restrict__ U2, const float* __restrict__ V2,
    ushort* __restrict__ U1t, ushort* __restrict__ V1t,
    ushort* __restrict__ U2t, ushort* __restrict__ V2t) {
  __shared__ float t[32][33];
  int blk = blockIdx.x;
  const float* in; ushort* out; int R, C, bx, by;
  if (blk < 288)       { in = U1; out = U1t; R = 768;  C = 384;  int i = blk;        bx = i % 12; by = i / 12; }
  else if (blk < 1440) { in = V1; out = V1t; R = 384;  C = 3072; int i = blk - 288;  bx = i % 96; by = i / 96; }
  else if (blk < 2592) { in = U2; out = U2t; R = 3072; C = 384;  int i = blk - 1440; bx = i % 12; by = i / 12; }
  else                 { in = V2; out = V2t; R = 384;  C = 768;  int i = blk - 2592; bx = i % 24; by = i / 24; }
  int c0 = bx * 32, r0 = by * 32;
  int lx = threadIdx.x & 31, ly = threadIdx.x >> 5;
#pragma unroll
  for (int i = 0; i < 32; i += 8)
    t[ly + i][lx] = in[(size_t)(r0 + ly + i) * C + c0 + lx];
  __syncthreads();
#pragma unroll
  for (int i = 0; i < 32; i += 8)
    out[(size_t)(c0 + ly + i) * R + r0 + lx] = f2b(t[lx][ly + i]);
}

// ---------------------------------------------------------------------------
// bf16 MFMA GEMM: C = A[M,K] @ Bt[N,K]^T (+bias) (+gelu)
// OUTMODE: 1 bf16 (M,N);
//          3 fused QKV: cols [0,768)->C (Q), [768,1536)->C2 (K),
//            [1536,2304)->C3 (V transposed (768, BM))
// 128x128 tile, BK=32, 256 threads.
// ---------------------------------------------------------------------------
template <int OUTMODE, int BIAS, int GELU>
__global__ __launch_bounds__(256) void gemm_mfma_kernel(
    const ushort* __restrict__ A, const ushort* __restrict__ Bt,
    const float* __restrict__ bias, void* __restrict__ C,
    void* __restrict__ C2, void* __restrict__ C3,
    int M, int N, int K) {
  __shared__ __align__(16) ushort Als[128 * 32];
  __shared__ __align__(16) ushort Bls[128 * 32];
  const int tid  = threadIdx.x;
  const int lane = tid & 63;
  const int quad = lane >> 4, l16 = lane & 15;
  const int wu   = __builtin_amdgcn_readfirstlane(tid >> 6);
  const int wrow = (wu >> 1) * 64, wcol = (wu & 1) * 64;
  const int row0 = blockIdx.y * 128, col0 = blockIdx.x * 128;

  floatx4 acc[4][4] = {};

  for (int k0 = 0; k0 < K; k0 += 32) {
    __syncthreads();
#pragma unroll
    for (int is = 0; is < 2; is++) {
      int c = is * 256 + wu * 64 + lane;
      int m = c >> 2, kk = (c & 3) << 3;
      const ushort* ga = A + (size_t)(row0 + m) * K + (k0 + kk);
      ushort* la = Als + (size_t)(is * 256 + wu * 64) * 8;
      __builtin_amdgcn_global_load_lds(
          (const __attribute__((address_space(1))) void*)ga,
          (__attribute__((address_space(3))) void*)la, 16, 0, 0);
      const ushort* gb = Bt + (size_t)(col0 + m) * K + (k0 + kk);
      ushort* lb = Bls + (size_t)(is * 256 + wu * 64) * 8;
      __builtin_amdgcn_global_load_lds(
          (const __attribute__((address_space(1))) void*)gb,
          (__attribute__((address_space(3))) void*)lb, 16, 0, 0);
    }
    __syncthreads();

    short8 af[4], bf[4];
#pragma unroll
    for (int mt = 0; mt < 4; mt++)
      af[mt] = *(const short8*)(Als + ((wrow + mt * 16 + l16) * 32 + quad * 8));
#pragma unroll
    for (int nt = 0; nt < 4; nt++)
      bf[nt] = *(const short8*)(Bls + ((wcol + nt * 16 + l16) * 32 + quad * 8));
#pragma unroll
    for (int mt = 0; mt < 4; mt++)
#pragma unroll
      for (int nt = 0; nt < 4; nt++)
        acc[mt][nt] = __builtin_amdgcn_mfma_f32_16x16x32_bf16(
            af[mt], bf[nt], acc[mt][nt], 0, 0, 0);
  }

#pragma unroll
  for (int mt = 0; mt < 4; mt++) {
#pragma unroll
    for (int nt = 0; nt < 4; nt++) {
      int colg = col0 + wcol + nt * 16 + l16;
      float bv_ = BIAS ? bias[colg] : 0.f;
      float v4[4];
#pragma unroll
      for (int r = 0; r < 4; r++) {
        float v = acc[mt][nt][r] + bv_;
        if (GELU) v = fast_gelu(v);
        v4[r] = v;
      }
      int rowg0 = row0 + wrow + mt * 16 + quad * 4;
      if (OUTMODE == 3) {
        int seg = col0 / 768;
        int cl = colg - seg * 768;
        if (seg == 2) {
          ushort4 o;
          o.x = f2b(v4[0]); o.y = f2b(v4[1]); o.z = f2b(v4[2]); o.w = f2b(v4[3]);
          *(ushort4*)((ushort*)C3 + (size_t)cl * BM + rowg0) = o;
        } else {
          ushort* dst = (seg == 0) ? (ushort*)C : (ushort*)C2;
#pragma unroll
          for (int r = 0; r < 4; r++)
            dst[(size_t)(rowg0 + r) * D_MODEL + cl] = f2b(v4[r]);
        }
      } else {
#pragma unroll
        for (int r = 0; r < 4; r++)
          ((ushort*)C)[(size_t)(rowg0 + r) * N + colg] = f2b(v4[r]);
      }
    }
  }
}

// ---------------------------------------------------------------------------
// 128x64-tile bf16 MFMA GEMM (+bias), bf16 out. grid (N/64, M/128).
// Used for N=768 GEMMs (K=384 or 768): 768 blocks -> 3 blocks/CU.
// ---------------------------------------------------------------------------
template <int BIAS>
__global__ __launch_bounds__(256) void gemm_n64_kernel(
    const ushort* __restrict__ A, const ushort* __restrict__ Bt,
    const float* __restrict__ bias, ushort* __restrict__ C,
    int M, int N, int K) {
  __shared__ __align__(16) ushort Als[128 * 32];
  __shared__ __align__(16) ushort Bls[64 * 32];
  const int tid  = threadIdx.x;
  const int lane = tid & 63;
  const int quad = lane >> 4, l16 = lane & 15;
  const int wu   = __builtin_amdgcn_readfirstlane(tid >> 6);
  const int row0 = blockIdx.y * 128, col0 = blockIdx.x * 64;

  floatx4 acc[2][4] = {};

  for (int k0 = 0; k0 < K; k0 += 32) {
    __syncthreads();
#pragma unroll
    for (int is = 0; is < 2; is++) {
      int c = is * 256 + wu * 64 + lane;
      int m = c >> 2, kk = (c & 3) << 3;
      const ushort* ga = A + (size_t)(row0 + m) * K + (k0 + kk);
      ushort* la = Als + (size_t)(is * 256 + wu * 64) * 8;
      __builtin_amdgcn_global_load_lds(
          (const __attribute__((address_space(1))) void*)ga,
          (__attribute__((address_space(3))) void*)la, 16, 0, 0);
    }
    {
      int c = wu * 64 + lane;
      int m = c >> 2, kk = (c & 3) << 3;
      const ushort* gb = Bt + (size_t)(col0 + m) * K + (k0 + kk);
      ushort* lb = Bls + (size_t)(wu * 64) * 8;
      __builtin_amdgcn_global_load_lds(
          (const __attribute__((address_space(1))) void*)gb,
          (__attribute__((address_space(3))) void*)lb, 16, 0, 0);
    }
    __syncthreads();

    short8 af[2], bf[4];
#pragma unroll
    for (int mt = 0; mt < 2; mt++)
      af[mt] = *(const short8*)(Als + ((wu * 32 + mt * 16 + l16) * 32 + quad * 8));
#pragma unroll
    for (int nt = 0; nt < 4; nt++)
      bf[nt] = *(const short8*)(Bls + ((nt * 16 + l16) * 32 + quad * 8));
#pragma unroll
    for (int mt = 0; mt < 2; mt++)
#pragma unroll
      for (int nt = 0; nt < 4; nt++)
        acc[mt][nt] = __builtin_amdgcn_mfma_f32_16x16x32_bf16(
            af[mt], bf[nt], acc[mt][nt], 0, 0, 0);
  }

#pragma unroll
  for (int mt = 0; mt < 2; mt++) {
#pragma unroll
    for (int nt = 0; nt < 4; nt++) {
      int colg = col0 + nt * 16 + l16;
      float bv_ = BIAS ? bias[colg] : 0.f;
      int rowg0 = row0 + wu * 32 + mt * 16 + quad * 4;
#pragma unroll
      for (int r = 0; r < 4; r++)
        C[(size_t)(rowg0 + r) * N + colg] = f2b(acc[mt][nt][r] + bv_);
    }
  }
}

// ---------------------------------------------------------------------------
// Split-K bf16 MFMA GEMM (fp32 partials) + reduce
// ---------------------------------------------------------------------------
__global__ __launch_bounds__(256) void gemm_mfma_splitk_kernel(
    const ushort* __restrict__ A, const ushort* __restrict__ Bt,
    float* __restrict__ Cpart, int M, int N, int Ktot, int Kper) {
  __shared__ __align__(16) ushort Als[128 * 32];
  __shared__ __align__(16) ushort Bls[128 * 32];
  const int tid  = threadIdx.x;
  const int lane = tid & 63;
  const int quad = lane >> 4, l16 = lane & 15;
  const int wu   = __builtin_amdgcn_readfirstlane(tid >> 6);
  const int wrow = (wu >> 1) * 64, wcol = (wu & 1) * 64;
  const int row0 = blockIdx.y * 128, col0 = blockIdx.x * 128;
  const int kbase = blockIdx.z * Kper;
  float* Cz = Cpart + (size_t)blockIdx.z * M * N;

  floatx4 acc[4][4] = {};

  for (int k0 = kbase; k0 < kbase + Kper; k0 += 32) {
    __syncthreads();
#pragma unroll
    for (int is = 0; is < 2; is++) {
      int c = is * 256 + wu * 64 + lane;
      int m = c >> 2, kk = (c & 3) << 3;
      const ushort* ga = A + (size_t)(row0 + m) * Ktot + (k0 + kk);
      ushort* la = Als + (size_t)(is * 256 + wu * 64) * 8;
      __builtin_amdgcn_global_load_lds(
          (const __attribute__((address_space(1))) void*)ga,
          (__attribute__((address_space(3))) void*)la, 16, 0, 0);
      const ushort* gb = Bt + (size_t)(col0 + m) * Ktot + (k0 + kk);
      ushort* lb = Bls + (size_t)(is * 256 + wu * 64) * 8;
      __builtin_amdgcn_global_load_lds(
          (const __attribute__((address_space(1))) void*)gb,
          (__attribute__((address_space(3))) void*)lb, 16, 0, 0);
    }
    __syncthreads();

    short8 af[4], bf[4];
#pragma unroll
    for (int mt = 0; mt < 4; mt++)
      af[mt] = *(const short8*)(Als + ((wrow + mt * 16 + l16) * 32 + quad * 8));
#pragma unroll
    for (int nt = 0; nt < 4; nt++)
      bf[nt] = *(const short8*)(Bls + ((wcol + nt * 16 + l16) * 32 + quad * 8));
#pragma unroll
    for (int mt = 0; mt < 4; mt++)
#pragma unroll
      for (int nt = 0; nt < 4; nt++)
        acc[mt][nt] = __builtin_amdgcn_mfma_f32_16x16x32_bf16(
            af[mt], bf[nt], acc[mt][nt], 0, 0, 0);
  }

#pragma unroll
  for (int mt = 0; mt < 4; mt++)
#pragma unroll
    for (int nt = 0; nt < 4; nt++) {
      int colg = col0 + wcol + nt * 16 + l16;
      int rowg0 = row0 + wrow + mt * 16 + quad * 4;
#pragma unroll
      for (int r = 0; r < 4; r++)
        Cz[(size_t)(rowg0 + r) * N + colg] = acc[mt][nt][r];
    }
}

__global__ __launch_bounds__(256) void reduce_splitk_kernel(
    const float* __restrict__ part, ushort* __restrict__ out, int n, int S) {
  int i = (blockIdx.x * 256 + threadIdx.x) * 4;
  if (i >= n) return;
  float4 a = *(const float4*)(part + i);
  for (int s = 1; s < S; s++) {
    float4 b = *(const float4*)(part + (size_t)s * n + i);
    a.x += b.x; a.y += b.y; a.z += b.z; a.w += b.w;
  }
  ushort4 o;
  o.x = f2b(a.x); o.y = f2b(a.y); o.z = f2b(a.z); o.w = f2b(a.w);
  *(ushort4*)(out + i) = o;
}

// ---------------------------------------------------------------------------
// MFMA flash attention v6 (r6, unchanged): coalesced LDS staging of K/V^T +
// in-register bf16 P-transpose via ds_bpermute. Block = 128 queries
// (4 waves x 32 rows), key chunks of 128. No softmax max-tracking (scores
// provably tiny). LDS 35840 B -> 3 blocks/CU.
// ---------------------------------------------------------------------------
__global__ __launch_bounds__(256, 3) void attn_mfma_kernel(
    const ushort* __restrict__ Q, const ushort* __restrict__ K,
    const ushort* __restrict__ Vt, const float* __restrict__ mask,
    ushort* __restrict__ O) {
  const int qt = blockIdx.x, h = blockIdx.y, b = blockIdx.z;
  const int tid = threadIdx.x;
  const int lane = tid & 63;
  const int quad = lane >> 4, l16 = lane & 15;
  const int wu = __builtin_amdgcn_readfirstlane(tid >> 6);
  const int qrow0 = qt * 128 + wu * 32;

  __shared__ __align__(16) ushort Ks[128 * 72];
  __shared__ __align__(16) ushort Vts[64 * 136];

  short8 qf[2][2];
#pragma unroll
  for (int rt = 0; rt < 2; rt++) {
    const ushort* qp = Q + ((size_t)(b * SEQ + qrow0 + rt * 16 + l16)) * D_MODEL
                     + h * DHEAD + quad * 8;
    qf[rt][0] = *(const short8*)qp;
    qf[rt][1] = *(const short8*)(qp + 32);
  }

  float lsum[2] = {0.f, 0.f};
  floatx4 o_acc[2][4] = {};
  const int base01 = (((quad & 1) << 5) | l16) << 2;
  const bool lotile = (quad < 2);

  for (int n0 = 0; n0 < SEQ; n0 += 128) {
    __syncthreads();
#pragma unroll
    for (int p = 0; p < 4; p++) {
      int cid = tid + p * 256;
      int j = cid >> 3, g = cid & 7;
      *(short8*)(Ks + j * 72 + g * 8) =
          *(const short8*)(K + ((size_t)(b * SEQ + n0 + j)) * D_MODEL + h * DHEAD + g * 8);
    }
#pragma unroll
    for (int p = 0; p < 4; p++) {
      int cid = tid + p * 256;
      int d = cid >> 4, g = cid & 15;
      *(short8*)(Vts + d * 136 + g * 8) =
          *(const short8*)(Vt + ((size_t)(h * DHEAD + d)) * BM + b * SEQ + n0 + g * 8);
    }
    __syncthreads();

    unsigned UA[2][8], UB[2][8];
#pragma unroll
    for (int ct = 0; ct < 8; ct++) {
      short8 ka = *(const short8*)(Ks + (ct * 16 + l16) * 72 + quad * 8);
      short8 kb = *(const short8*)(Ks + (ct * 16 + l16) * 72 + 32 + quad * 8);
      float4 mk = *(const float4*)(mask + (size_t)b * SEQ + n0 + ct * 16 + quad * 4);
#pragma unroll
      for (int rt = 0; rt < 2; rt++) {
        floatx4 st = {};
        st = __builtin_amdgcn_mfma_f32_16x16x32_bf16(ka, qf[rt][0], st, 0, 0, 0);
        st = __builtin_amdgcn_mfma_f32_16x16x32_bf16(kb, qf[rt][1], st, 0, 0, 0);
        float e0 = __expf(st[0] * 0.125f + mk.x);
        float e1 = __expf(st[1] * 0.125f + mk.y);
        float e2 = __expf(st[2] * 0.125f + mk.z);
        float e3 = __expf(st[3] * 0.125f + mk.w);
        lsum[rt] += (e0 + e1) + (e2 + e3);
        UA[rt][ct] = pk2(e0, e1);
        UB[rt][ct] = pk2(e2, e3);
      }
    }

#pragma unroll
    for (int kk = 0; kk < 4; kk++) {
      short8 pa[2];
#pragma unroll
      for (int rt = 0; rt < 2; rt++) {
        int a0 = __builtin_amdgcn_ds_bpermute(base01, (int)UA[rt][2 * kk]);
        int a1 = __builtin_amdgcn_ds_bpermute(base01, (int)UA[rt][2 * kk + 1]);
        int b0 = __builtin_amdgcn_ds_bpermute(base01, (int)UB[rt][2 * kk]);
        int b1 = __builtin_amdgcn_ds_bpermute(base01, (int)UB[rt][2 * kk + 1]);
        int c0 = __builtin_amdgcn_ds_bpermute(base01 + 64, (int)UA[rt][2 * kk]);
        int c1 = __builtin_amdgcn_ds_bpermute(base01 + 64, (int)UA[rt][2 * kk + 1]);
        int d0 = __builtin_amdgcn_ds_bpermute(base01 + 64, (int)UB[rt][2 * kk]);
        int d1 = __builtin_amdgcn_ds_bpermute(base01 + 64, (int)UB[rt][2 * kk + 1]);
        int4 t;
        t.x = lotile ? a0 : a1;
        t.y = lotile ? b0 : b1;
        t.z = lotile ? c0 : c1;
        t.w = lotile ? d0 : d1;
        pa[rt] = *(short8*)&t;
      }
#pragma unroll
      for (int dt = 0; dt < 4; dt++) {
        short8 vb = *(const short8*)(Vts + (dt * 16 + l16) * 136 + kk * 32 + quad * 8);
#pragma unroll
        for (int rt = 0; rt < 2; rt++)
          o_acc[rt][dt] = __builtin_amdgcn_mfma_f32_16x16x32_bf16(pa[rt], vb, o_acc[rt][dt], 0, 0, 0);
      }
    }
  }

#pragma unroll
  for (int rt = 0; rt < 2; rt++) {
    float l = lsum[rt];
    l += __shfl_xor(l, 16);
    l += __shfl_xor(l, 32);
    float inv = 1.f / l;
    int lanebase = lane & 48;
#pragma unroll
    for (int rr = 0; rr < 4; rr++) {
      int iv = __builtin_amdgcn_ds_bpermute((lanebase | (quad * 4 + rr)) << 2,
                                            __float_as_int(inv));
      float invr = __int_as_float(iv);
      size_t rowg = (size_t)(b * SEQ + qrow0 + rt * 16 + quad * 4 + rr);
#pragma unroll
      for (int dt = 0; dt < 4; dt++)
        O[rowg * D_MODEL + h * DHEAD + dt * 16 + l16] = f2b(o_acc[rt][dt][rr] * invr);
    }
  }
}

// ---------------------------------------------------------------------------
// out = LayerNorm(Ain + Bin)*g + bt. Bin bf16. Ain fp32 or bf16.
// ---------------------------------------------------------------------------
template <int AIN_BF16, int OUT_FP32, int OUT_BF16>
__global__ __launch_bounds__(256) void add_ln_kernel(
    const float* __restrict__ Ainf, const ushort* __restrict__ Ainb,
    const ushort* __restrict__ Binb,
    const float* __restrict__ g, const float* __restrict__ bt,
    float* __restrict__ outf, ushort* __restrict__ outb) {
  const int row = blockIdx.x, tid = threadIdx.x;
  __shared__ float red[4];
  float v[3];
  float s = 0.f;
#pragma unroll
  for (int u = 0; u < 3; u++) {
    int c = tid + u * 256;
    float a = AIN_BF16 ? b2f(Ainb[(size_t)row * 768 + c]) : Ainf[(size_t)row * 768 + c];
    v[u] = a + b2f(Binb[(size_t)row * 768 + c]);
    s += v[u];
  }
#pragma unroll
  for (int off = 32; off > 0; off >>= 1) s += __shfl_down(s, off);
  if ((tid & 63) == 0) red[tid >> 6] = s;
  __syncthreads();
  float mu = (red[0] + red[1] + red[2] + red[3]) * (1.f / 768.f);
  float s2 = 0.f;
#pragma unroll
  for (int u = 0; u < 3; u++) { float d = v[u] - mu; s2 += d * d; }
#pragma unroll
  for (int off = 32; off > 0; off >>= 1) s2 += __shfl_down(s2, off);
  __syncthreads();
  if ((tid & 63) == 0) red[tid >> 6] = s2;
  __syncthreads();
  float var = (red[0] + red[1] + red[2] + red[3]) * (1.f / 768.f);
  float inv = rsqrtf(var + 1e-12f);
#pragma unroll
  for (int u = 0; u < 3; u++) {
    int c = tid + u * 256;
    float r = g[c] * (v[u] - mu) * inv + bt[c];
    if (OUT_FP32) outf[(size_t)row * 768 + c] = r;
    if (OUT_BF16) outb[(size_t)row * 768 + c] = f2b(r);
  }
}

// ---------------------------------------------------------------------------
extern "C" void kernel_launch(void* const* d_in, const int* in_sizes, int n_in,
                              void* d_out, int out_size, void* d_ws, size_t ws_size,
                              hipStream_t stream) {
  const float* x    = (const float*)d_in[0];
  const float* mask = (const float*)d_in[1];
  const float* Pq   = (const float*)d_in[2];
  const float* Vq   = (const float*)d_in[3];
  const float* bq   = (const float*)d_in[4];
  const float* Pk   = (const float*)d_in[5];
  const float* Vk   = (const float*)d_in[6];
  const float* bk   = (const float*)d_in[7];
  const float* Pv   = (const float*)d_in[8];
  const float* Vv   = (const float*)d_in[9];
  const float* bv   = (const float*)d_in[10];
  const float* Uo   = (const float*)d_in[11];
  const float* Vo   = (const float*)d_in[12];
  const float* bo   = (const float*)d_in[13];
  const float* U1   = (const float*)d_in[14];
  const float* V1   = (const float*)d_in[15];
  const float* b1   = (const float*)d_in[16];
  const float* U2   = (const float*)d_in[17];
  const float* V2   = (const float*)d_in[18];
  const float* b2   = (const float*)d_in[19];
  const float* g1   = (const float*)d_in[20];
  const float* be1  = (const float*)d_in[21];
  const float* g2   = (const float*)d_in[22];
  const float* be2  = (const float*)d_in[23];

  // --- workspace carve (bytes, 256-aligned) ---
  char* w = (char*)d_ws;
  auto alloc = [&](size_t bytes) -> char* {
    char* p = w; w += (bytes + 255) & ~(size_t)255; return p;
  };
  ushort* xb     = (ushort*)alloc((size_t)BM * 768 * 2);
  ushort* Wqkvt  = (ushort*)alloc((size_t)2304 * 768 * 2);
  float*  ball   = (float*)alloc(2304 * 4);
  ushort* Wot    = (ushort*)alloc(768 * 768 * 2);
  ushort* U1t    = (ushort*)alloc(384 * 768 * 2);
  ushort* V1t    = (ushort*)alloc((size_t)3072 * 384 * 2);
  ushort* U2t    = (ushort*)alloc((size_t)384 * 3072 * 2);
  ushort* V2t    = (ushort*)alloc(768 * 384 * 2);
  ushort* Qb     = (ushort*)alloc((size_t)BM * 768 * 2);
  ushort* Kb     = (ushort*)alloc((size_t)BM * 768 * 2);
  ushort* Vtb    = (ushort*)alloc((size_t)768 * BM * 2);
  ushort* attnb  = (ushort*)alloc((size_t)BM * 768 * 2);
  ushort* mtb    = (ushort*)alloc((size_t)BM * 384 * 2);   // mid / t2
  ushort* y1b    = (ushort*)alloc((size_t)BM * 768 * 2);
  ushort* x1b    = (ushort*)alloc((size_t)BM * 768 * 2);
  float*  part   = (float*)alloc((size_t)4 * BM * 384 * 4);
  // aliases (dead-buffer reuse)
  ushort* hiddenb = Qb;             // Qb..attnb (50.3 MB) dead after y1 GEMM
  ushort* y2b     = y1b;            // y1b dead after LN1
  float*  outp    = (float*)d_out;

  // 1) conversions / weight prep (5 launches)
  f2b_kernel<<<(BM * 768) / 1024, 256, 0, stream>>>(x, xb, BM * 768);
  combine_qkv_kernel<<<dim3(2304, 3), 256, 0, stream>>>(Pq, Vq, Pk, Vk, Pv, Vv, Wqkvt);
  concat_bias_kernel<<<9, 256, 0, stream>>>(bq, bk, bv, ball);
  combine_wo_kernel<<<2304, 256, 0, stream>>>(Uo, Vo, Wot);
  transpose4_kernel<<<2880, 256, 0, stream>>>(U1, V1, U2, V2, U1t, V1t, U2t, V2t);

  // 2) fused QKV = x @ [Wq|Wk|Wv] + bias  (Q,K token-major; V transposed)
  gemm_mfma_kernel<3, 1, 0><<<dim3(18, 64), 256, 0, stream>>>(
      xb, Wqkvt, ball, Qb, Kb, Vtb, BM, 2304, 768);

  // 3) MFMA flash attention -> bf16 (B*M, 768)
  attn_mfma_kernel<<<dim3(8, 12, 8), 256, 0, stream>>>(Qb, Kb, Vtb, mask, attnb);

  // 4) attn out-projection: y1 = attn @ Wo + bo  (full-rank precombined)
  gemm_n64_kernel<1><<<dim3(12, 64), 256, 0, stream>>>(attnb, Wot, bo, y1b, BM, 768, 768);
  add_ln_kernel<0, 0, 1><<<BM, 256, 0, stream>>>(x, nullptr, y1b, g1, be1, nullptr, x1b);

  // 5) FFN (low rank) with fast GELU
  gemm_mfma_splitk_kernel<<<dim3(3, 64, 4), 256, 0, stream>>>(
      x1b, U1t, part, BM, 384, 768, 192);
  reduce_splitk_kernel<<<(BM * 384) / 1024, 256, 0, stream>>>(part, mtb, BM * 384, 4);
  gemm_mfma_kernel<1, 1, 1><<<dim3(24, 64), 256, 0, stream>>>(
      mtb, V1t, b1, hiddenb, nullptr, nullptr, BM, 3072, 384);
  gemm_mfma_splitk_kernel<<<dim3(3, 64, 4), 256, 0, stream>>>(
      hiddenb, U2t, part, BM, 384, 3072, 768);
  reduce_splitk_kernel<<<(BM * 384) / 1024, 256, 0, stream>>>(part, mtb, BM * 384, 4);
  gemm_n64_kernel<1><<<dim3(12, 64), 256, 0, stream>>>(mtb, V2t, b2, y2b, BM, 768, 384);

  // 6) residual + LN2 -> output (fp32)
  add_ln_kernel<1, 1, 0><<<BM, 256, 0, stream>>>(nullptr, x1b, y2b, g2, be2, outp, nullptr);
}

// Round 8
// 461.259 us; speedup vs baseline: 1.3821x; 1.3821x over previous
//
#include <hip/hip_runtime.h>
#include <cstddef>

// Problem constants
#define D_MODEL 768
#define NHEAD   12
#define DHEAD   64
#define RANK    32
#define SEQ     1024
#define BATCH   8
#define BM      8192      // BATCH*SEQ

typedef __attribute__((ext_vector_type(8))) short short8;
typedef __attribute__((ext_vector_type(4))) float floatx4;

__device__ inline ushort f2b(float f) {           // fp32 -> bf16 RNE
  union { float f; unsigned u; } v; v.f = f;
  unsigned r = v.u + 0x7fffu + ((v.u >> 16) & 1u);
  return (ushort)(r >> 16);
}
__device__ inline float b2f(ushort h) {
  union { unsigned u; float f; } v; v.u = ((unsigned)h) << 16;
  return v.f;
}
// pack two fp32 -> bf16x2 dword
__device__ inline unsigned pk2(float a, float b) {
  return ((__float_as_uint(b) + 0x8000u) & 0xffff0000u) |
         ((__float_as_uint(a) + 0x8000u) >> 16);
}
// tanh-form GELU with fast exp (max |err vs erf-GELU| ~1e-3)
__device__ inline float fast_gelu(float x) {
  float z = 0.79788456080286536f * (x + 0.044715f * x * x * x);
  float e = __expf(2.f * z);
  float t = 1.f - 2.f / (e + 1.f);
  return 0.5f * x * (1.f + t);
}

// ---------------------------------------------------------------------------
__global__ __launch_bounds__(256) void f2b_kernel(
    const float* __restrict__ in, ushort* __restrict__ out, int n) {
  int i = (blockIdx.x * 256 + threadIdx.x) * 4;
  if (i >= n) return;
  float4 v = *(const float4*)(in + i);
  ushort4 o;
  o.x = f2b(v.x); o.y = f2b(v.y); o.z = f2b(v.z); o.w = f2b(v.w);
  *(ushort4*)(out + i) = o;
}

// ---------------------------------------------------------------------------
// All three QKV low-rank combines in one launch (grid.y selects q/k/v):
// Wt[y][c=h*64+k][d] = sum_r P[h,d,r] * Vw[h,r,k]
// ---------------------------------------------------------------------------
__global__ __launch_bounds__(256) void combine_qkv_kernel(
    const float* __restrict__ Pq, const float* __restrict__ Vq,
    const float* __restrict__ Pk, const float* __restrict__ Vk,
    const float* __restrict__ Pv, const float* __restrict__ Vv,
    ushort* __restrict__ Wt) {
  int which = blockIdx.y;
  const float* P  = which == 0 ? Pq : (which == 1 ? Pk : Pv);
  const float* Vw = which == 0 ? Vq : (which == 1 ? Vk : Vv);
  ushort* W = Wt + (size_t)which * D_MODEL * D_MODEL;
  int idx = blockIdx.x * 256 + threadIdx.x;
  if (idx >= D_MODEL * NHEAD * DHEAD) return;
  int c = idx / D_MODEL;
  int d = idx - c * D_MODEL;
  int h = c >> 6, k = c & 63;
  const float* p = P + ((size_t)h * D_MODEL + d) * RANK;
  const float* v = Vw + (size_t)h * RANK * DHEAD + k;
  float s = 0.f;
#pragma unroll
  for (int r = 0; r < RANK; r++) s += p[r] * v[(size_t)r * DHEAD];
  W[(size_t)c * D_MODEL + d] = f2b(s);
}

__global__ __launch_bounds__(256) void concat_bias_kernel(
    const float* __restrict__ bq, const float* __restrict__ bk,
    const float* __restrict__ bv, float* __restrict__ out) {
  int i = blockIdx.x * 256 + threadIdx.x;
  if (i >= 2304) return;
  out[i] = (i < 768) ? bq[i] : (i < 1536 ? bk[i - 768] : bv[i - 1536]);
}

// ---------------------------------------------------------------------------
// Six weight preps in one launch (block-range decode):
// transposes (fp32 (R,C) -> bf16 (C,R)): U1(768,384) V1(384,3072)
//   U2(3072,384) V2(384,768) Vo(384,768)
// plus straight f2b copy of Uo (768x384) for the Wot GEMM's Bt operand.
// ---------------------------------------------------------------------------
__global__ __launch_bounds__(256) void prep_weights_kernel(
    const float* __restrict__ U1, const float* __restrict__ V1,
    const float* __restrict__ U2, const float* __restrict__ V2,
    const float* __restrict__ Vo, const float* __restrict__ Uo,
    ushort* __restrict__ U1t, ushort* __restrict__ V1t,
    ushort* __restrict__ U2t, ushort* __restrict__ V2t,
    ushort* __restrict__ VoT, ushort* __restrict__ Uob) {
  __shared__ float t[32][33];
  int blk = blockIdx.x;
  if (blk >= 3168) {                 // Uo f2b copy: 288 blocks x 1024 elems
    int i = (blk - 3168) * 1024 + threadIdx.x * 4;
    float4 v = *(const float4*)(Uo + i);
    ushort4 o;
    o.x = f2b(v.x); o.y = f2b(v.y); o.z = f2b(v.z); o.w = f2b(v.w);
    *(ushort4*)(Uob + i) = o;
    return;
  }
  const float* in; ushort* out; int R, C, bx, by;
  if (blk < 288)       { in = U1; out = U1t; R = 768;  C = 384;  int i = blk;        bx = i % 12; by = i / 12; }
  else if (blk < 1440) { in = V1; out = V1t; R = 384;  C = 3072; int i = blk - 288;  bx = i % 96; by = i / 96; }
  else if (blk < 2592) { in = U2; out = U2t; R = 3072; C = 384;  int i = blk - 1440; bx = i % 12; by = i / 12; }
  else if (blk < 2880) { in = V2; out = V2t; R = 384;  C = 768;  int i = blk - 2592; bx = i % 24; by = i / 24; }
  else                 { in = Vo; out = VoT; R = 384;  C = 768;  int i = blk - 2880; bx = i % 24; by = i / 24; }
  int c0 = bx * 32, r0 = by * 32;
  int lx = threadIdx.x & 31, ly = threadIdx.x >> 5;
#pragma unroll
  for (int i = 0; i < 32; i += 8)
    t[ly + i][lx] = in[(size_t)(r0 + ly + i) * C + c0 + lx];
  __syncthreads();
#pragma unroll
  for (int i = 0; i < 32; i += 8)
    out[(size_t)(c0 + ly + i) * R + r0 + lx] = f2b(t[lx][ly + i]);
}

// ---------------------------------------------------------------------------
// bf16 MFMA GEMM: C = A[M,K] @ Bt[N,K]^T (+bias) (+gelu)
// OUTMODE: 1 bf16 (M,N);
//          3 fused QKV: cols [0,768)->C (Q), [768,1536)->C2 (K),
//            [1536,2304)->C3 (V transposed (768, BM))
// 128x128 tile, BK=32, 256 threads.
// ---------------------------------------------------------------------------
template <int OUTMODE, int BIAS, int GELU>
__global__ __launch_bounds__(256) void gemm_mfma_kernel(
    const ushort* __restrict__ A, const ushort* __restrict__ Bt,
    const float* __restrict__ bias, void* __restrict__ C,
    void* __restrict__ C2, void* __restrict__ C3,
    int M, int N, int K) {
  __shared__ __align__(16) ushort Als[128 * 32];
  __shared__ __align__(16) ushort Bls[128 * 32];
  const int tid  = threadIdx.x;
  const int lane = tid & 63;
  const int quad = lane >> 4, l16 = lane & 15;
  const int wu   = __builtin_amdgcn_readfirstlane(tid >> 6);
  const int wrow = (wu >> 1) * 64, wcol = (wu & 1) * 64;
  const int row0 = blockIdx.y * 128, col0 = blockIdx.x * 128;

  floatx4 acc[4][4] = {};

  for (int k0 = 0; k0 < K; k0 += 32) {
    __syncthreads();
#pragma unroll
    for (int is = 0; is < 2; is++) {
      int c = is * 256 + wu * 64 + lane;
      int m = c >> 2, kk = (c & 3) << 3;
      const ushort* ga = A + (size_t)(row0 + m) * K + (k0 + kk);
      ushort* la = Als + (size_t)(is * 256 + wu * 64) * 8;
      __builtin_amdgcn_global_load_lds(
          (const __attribute__((address_space(1))) void*)ga,
          (__attribute__((address_space(3))) void*)la, 16, 0, 0);
      const ushort* gb = Bt + (size_t)(col0 + m) * K + (k0 + kk);
      ushort* lb = Bls + (size_t)(is * 256 + wu * 64) * 8;
      __builtin_amdgcn_global_load_lds(
          (const __attribute__((address_space(1))) void*)gb,
          (__attribute__((address_space(3))) void*)lb, 16, 0, 0);
    }
    __syncthreads();

    short8 af[4], bf[4];
#pragma unroll
    for (int mt = 0; mt < 4; mt++)
      af[mt] = *(const short8*)(Als + ((wrow + mt * 16 + l16) * 32 + quad * 8));
#pragma unroll
    for (int nt = 0; nt < 4; nt++)
      bf[nt] = *(const short8*)(Bls + ((wcol + nt * 16 + l16) * 32 + quad * 8));
#pragma unroll
    for (int mt = 0; mt < 4; mt++)
#pragma unroll
      for (int nt = 0; nt < 4; nt++)
        acc[mt][nt] = __builtin_amdgcn_mfma_f32_16x16x32_bf16(
            af[mt], bf[nt], acc[mt][nt], 0, 0, 0);
  }

#pragma unroll
  for (int mt = 0; mt < 4; mt++) {
#pragma unroll
    for (int nt = 0; nt < 4; nt++) {
      int colg = col0 + wcol + nt * 16 + l16;
      float bv_ = BIAS ? bias[colg] : 0.f;
      float v4[4];
#pragma unroll
      for (int r = 0; r < 4; r++) {
        float v = acc[mt][nt][r] + bv_;
        if (GELU) v = fast_gelu(v);
        v4[r] = v;
      }
      int rowg0 = row0 + wrow + mt * 16 + quad * 4;
      if (OUTMODE == 3) {
        int seg = col0 / 768;
        int cl = colg - seg * 768;
        if (seg == 2) {
          ushort4 o;
          o.x = f2b(v4[0]); o.y = f2b(v4[1]); o.z = f2b(v4[2]); o.w = f2b(v4[3]);
          *(ushort4*)((ushort*)C3 + (size_t)cl * BM + rowg0) = o;
        } else {
          ushort* dst = (seg == 0) ? (ushort*)C : (ushort*)C2;
#pragma unroll
          for (int r = 0; r < 4; r++)
            dst[(size_t)(rowg0 + r) * D_MODEL + cl] = f2b(v4[r]);
        }
      } else {
#pragma unroll
        for (int r = 0; r < 4; r++)
          ((ushort*)C)[(size_t)(rowg0 + r) * N + colg] = f2b(v4[r]);
      }
    }
  }
}

// ---------------------------------------------------------------------------
// 128x64-tile bf16 MFMA GEMM (+bias), bf16 out. grid (N/64, M/128).
// ---------------------------------------------------------------------------
template <int BIAS>
__global__ __launch_bounds__(256) void gemm_n64_kernel(
    const ushort* __restrict__ A, const ushort* __restrict__ Bt,
    const float* __restrict__ bias, ushort* __restrict__ C,
    int M, int N, int K) {
  __shared__ __align__(16) ushort Als[128 * 32];
  __shared__ __align__(16) ushort Bls[64 * 32];
  const int tid  = threadIdx.x;
  const int lane = tid & 63;
  const int quad = lane >> 4, l16 = lane & 15;
  const int wu   = __builtin_amdgcn_readfirstlane(tid >> 6);
  const int row0 = blockIdx.y * 128, col0 = blockIdx.x * 64;

  floatx4 acc[2][4] = {};

  for (int k0 = 0; k0 < K; k0 += 32) {
    __syncthreads();
#pragma unroll
    for (int is = 0; is < 2; is++) {
      int c = is * 256 + wu * 64 + lane;
      int m = c >> 2, kk = (c & 3) << 3;
      const ushort* ga = A + (size_t)(row0 + m) * K + (k0 + kk);
      ushort* la = Als + (size_t)(is * 256 + wu * 64) * 8;
      __builtin_amdgcn_global_load_lds(
          (const __attribute__((address_space(1))) void*)ga,
          (__attribute__((address_space(3))) void*)la, 16, 0, 0);
    }
    {
      int c = wu * 64 + lane;
      int m = c >> 2, kk = (c & 3) << 3;
      const ushort* gb = Bt + (size_t)(col0 + m) * K + (k0 + kk);
      ushort* lb = Bls + (size_t)(wu * 64) * 8;
      __builtin_amdgcn_global_load_lds(
          (const __attribute__((address_space(1))) void*)gb,
          (__attribute__((address_space(3))) void*)lb, 16, 0, 0);
    }
    __syncthreads();

    short8 af[2], bf[4];
#pragma unroll
    for (int mt = 0; mt < 2; mt++)
      af[mt] = *(const short8*)(Als + ((wu * 32 + mt * 16 + l16) * 32 + quad * 8));
#pragma unroll
    for (int nt = 0; nt < 4; nt++)
      bf[nt] = *(const short8*)(Bls + ((nt * 16 + l16) * 32 + quad * 8));
#pragma unroll
    for (int mt = 0; mt < 2; mt++)
#pragma unroll
      for (int nt = 0; nt < 4; nt++)
        acc[mt][nt] = __builtin_amdgcn_mfma_f32_16x16x32_bf16(
            af[mt], bf[nt], acc[mt][nt], 0, 0, 0);
  }

#pragma unroll
  for (int mt = 0; mt < 2; mt++) {
#pragma unroll
    for (int nt = 0; nt < 4; nt++) {
      int colg = col0 + nt * 16 + l16;
      float bv_ = BIAS ? bias[colg] : 0.f;
      int rowg0 = row0 + wu * 32 + mt * 16 + quad * 4;
#pragma unroll
      for (int r = 0; r < 4; r++)
        C[(size_t)(rowg0 + r) * N + colg] = f2b(acc[mt][nt][r] + bv_);
    }
  }
}

// ---------------------------------------------------------------------------
// Split-K bf16 MFMA GEMM (fp32 partials) + reduce
// ---------------------------------------------------------------------------
__global__ __launch_bounds__(256) void gemm_mfma_splitk_kernel(
    const ushort* __restrict__ A, const ushort* __restrict__ Bt,
    float* __restrict__ Cpart, int M, int N, int Ktot, int Kper) {
  __shared__ __align__(16) ushort Als[128 * 32];
  __shared__ __align__(16) ushort Bls[128 * 32];
  const int tid  = threadIdx.x;
  const int lane = tid & 63;
  const int quad = lane >> 4, l16 = lane & 15;
  const int wu   = __builtin_amdgcn_readfirstlane(tid >> 6);
  const int wrow = (wu >> 1) * 64, wcol = (wu & 1) * 64;
  const int row0 = blockIdx.y * 128, col0 = blockIdx.x * 128;
  const int kbase = blockIdx.z * Kper;
  float* Cz = Cpart + (size_t)blockIdx.z * M * N;

  floatx4 acc[4][4] = {};

  for (int k0 = kbase; k0 < kbase + Kper; k0 += 32) {
    __syncthreads();
#pragma unroll
    for (int is = 0; is < 2; is++) {
      int c = is * 256 + wu * 64 + lane;
      int m = c >> 2, kk = (c & 3) << 3;
      const ushort* ga = A + (size_t)(row0 + m) * Ktot + (k0 + kk);
      ushort* la = Als + (size_t)(is * 256 + wu * 64) * 8;
      __builtin_amdgcn_global_load_lds(
          (const __attribute__((address_space(1))) void*)ga,
          (__attribute__((address_space(3))) void*)la, 16, 0, 0);
      const ushort* gb = Bt + (size_t)(col0 + m) * Ktot + (k0 + kk);
      ushort* lb = Bls + (size_t)(is * 256 + wu * 64) * 8;
      __builtin_amdgcn_global_load_lds(
          (const __attribute__((address_space(1))) void*)gb,
          (__attribute__((address_space(3))) void*)lb, 16, 0, 0);
    }
    __syncthreads();

    short8 af[4], bf[4];
#pragma unroll
    for (int mt = 0; mt < 4; mt++)
      af[mt] = *(const short8*)(Als + ((wrow + mt * 16 + l16) * 32 + quad * 8));
#pragma unroll
    for (int nt = 0; nt < 4; nt++)
      bf[nt] = *(const short8*)(Bls + ((wcol + nt * 16 + l16) * 32 + quad * 8));
#pragma unroll
    for (int mt = 0; mt < 4; mt++)
#pragma unroll
      for (int nt = 0; nt < 4; nt++)
        acc[mt][nt] = __builtin_amdgcn_mfma_f32_16x16x32_bf16(
            af[mt], bf[nt], acc[mt][nt], 0, 0, 0);
  }

#pragma unroll
  for (int mt = 0; mt < 4; mt++)
#pragma unroll
    for (int nt = 0; nt < 4; nt++) {
      int colg = col0 + wcol + nt * 16 + l16;
      int rowg0 = row0 + wrow + mt * 16 + quad * 4;
#pragma unroll
      for (int r = 0; r < 4; r++)
        Cz[(size_t)(rowg0 + r) * N + colg] = acc[mt][nt][r];
    }
}

__global__ __launch_bounds__(256) void reduce_splitk_kernel(
    const float* __restrict__ part, ushort* __restrict__ out, int n, int S) {
  int i = (blockIdx.x * 256 + threadIdx.x) * 4;
  if (i >= n) return;
  float4 a = *(const float4*)(part + i);
  for (int s = 1; s < S; s++) {
    float4 b = *(const float4*)(part + (size_t)s * n + i);
    a.x += b.x; a.y += b.y; a.z += b.z; a.w += b.w;
  }
  ushort4 o;
  o.x = f2b(a.x); o.y = f2b(a.y); o.z = f2b(a.z); o.w = f2b(a.w);
  *(ushort4*)(out + i) = o;
}

// ---------------------------------------------------------------------------
// MFMA flash attention v6 (r6, unchanged): coalesced LDS staging of K/V^T +
// in-register bf16 P-transpose via ds_bpermute. Block = 128 queries
// (4 waves x 32 rows), key chunks of 128. No softmax max-tracking (scores
// provably tiny). LDS 35840 B -> 3 blocks/CU.
// ---------------------------------------------------------------------------
__global__ __launch_bounds__(256, 3) void attn_mfma_kernel(
    const ushort* __restrict__ Q, const ushort* __restrict__ K,
    const ushort* __restrict__ Vt, const float* __restrict__ mask,
    ushort* __restrict__ O) {
  const int qt = blockIdx.x, h = blockIdx.y, b = blockIdx.z;
  const int tid = threadIdx.x;
  const int lane = tid & 63;
  const int quad = lane >> 4, l16 = lane & 15;
  const int wu = __builtin_amdgcn_readfirstlane(tid >> 6);
  const int qrow0 = qt * 128 + wu * 32;

  __shared__ __align__(16) ushort Ks[128 * 72];
  __shared__ __align__(16) ushort Vts[64 * 136];

  short8 qf[2][2];
#pragma unroll
  for (int rt = 0; rt < 2; rt++) {
    const ushort* qp = Q + ((size_t)(b * SEQ + qrow0 + rt * 16 + l16)) * D_MODEL
                     + h * DHEAD + quad * 8;
    qf[rt][0] = *(const short8*)qp;
    qf[rt][1] = *(const short8*)(qp + 32);
  }

  float lsum[2] = {0.f, 0.f};
  floatx4 o_acc[2][4] = {};
  const int base01 = (((quad & 1) << 5) | l16) << 2;
  const bool lotile = (quad < 2);

  for (int n0 = 0; n0 < SEQ; n0 += 128) {
    __syncthreads();
#pragma unroll
    for (int p = 0; p < 4; p++) {
      int cid = tid + p * 256;
      int j = cid >> 3, g = cid & 7;
      *(short8*)(Ks + j * 72 + g * 8) =
          *(const short8*)(K + ((size_t)(b * SEQ + n0 + j)) * D_MODEL + h * DHEAD + g * 8);
    }
#pragma unroll
    for (int p = 0; p < 4; p++) {
      int cid = tid + p * 256;
      int d = cid >> 4, g = cid & 15;
      *(short8*)(Vts + d * 136 + g * 8) =
          *(const short8*)(Vt + ((size_t)(h * DHEAD + d)) * BM + b * SEQ + n0 + g * 8);
    }
    __syncthreads();

    unsigned UA[2][8], UB[2][8];
#pragma unroll
    for (int ct = 0; ct < 8; ct++) {
      short8 ka = *(const short8*)(Ks + (ct * 16 + l16) * 72 + quad * 8);
      short8 kb = *(const short8*)(Ks + (ct * 16 + l16) * 72 + 32 + quad * 8);
      float4 mk = *(const float4*)(mask + (size_t)b * SEQ + n0 + ct * 16 + quad * 4);
#pragma unroll
      for (int rt = 0; rt < 2; rt++) {
        floatx4 st = {};
        st = __builtin_amdgcn_mfma_f32_16x16x32_bf16(ka, qf[rt][0], st, 0, 0, 0);
        st = __builtin_amdgcn_mfma_f32_16x16x32_bf16(kb, qf[rt][1], st, 0, 0, 0);
        float e0 = __expf(st[0] * 0.125f + mk.x);
        float e1 = __expf(st[1] * 0.125f + mk.y);
        float e2 = __expf(st[2] * 0.125f + mk.z);
        float e3 = __expf(st[3] * 0.125f + mk.w);
        lsum[rt] += (e0 + e1) + (e2 + e3);
        UA[rt][ct] = pk2(e0, e1);
        UB[rt][ct] = pk2(e2, e3);
      }
    }

#pragma unroll
    for (int kk = 0; kk < 4; kk++) {
      short8 pa[2];
#pragma unroll
      for (int rt = 0; rt < 2; rt++) {
        int a0 = __builtin_amdgcn_ds_bpermute(base01, (int)UA[rt][2 * kk]);
        int a1 = __builtin_amdgcn_ds_bpermute(base01, (int)UA[rt][2 * kk + 1]);
        int b0 = __builtin_amdgcn_ds_bpermute(base01, (int)UB[rt][2 * kk]);
        int b1 = __builtin_amdgcn_ds_bpermute(base01, (int)UB[rt][2 * kk + 1]);
        int c0 = __builtin_amdgcn_ds_bpermute(base01 + 64, (int)UA[rt][2 * kk]);
        int c1 = __builtin_amdgcn_ds_bpermute(base01 + 64, (int)UA[rt][2 * kk + 1]);
        int d0 = __builtin_amdgcn_ds_bpermute(base01 + 64, (int)UB[rt][2 * kk]);
        int d1 = __builtin_amdgcn_ds_bpermute(base01 + 64, (int)UB[rt][2 * kk + 1]);
        int4 t;
        t.x = lotile ? a0 : a1;
        t.y = lotile ? b0 : b1;
        t.z = lotile ? c0 : c1;
        t.w = lotile ? d0 : d1;
        pa[rt] = *(short8*)&t;
      }
#pragma unroll
      for (int dt = 0; dt < 4; dt++) {
        short8 vb = *(const short8*)(Vts + (dt * 16 + l16) * 136 + kk * 32 + quad * 8);
#pragma unroll
        for (int rt = 0; rt < 2; rt++)
          o_acc[rt][dt] = __builtin_amdgcn_mfma_f32_16x16x32_bf16(pa[rt], vb, o_acc[rt][dt], 0, 0, 0);
      }
    }
  }

#pragma unroll
  for (int rt = 0; rt < 2; rt++) {
    float l = lsum[rt];
    l += __shfl_xor(l, 16);
    l += __shfl_xor(l, 32);
    float inv = 1.f / l;
    int lanebase = lane & 48;
#pragma unroll
    for (int rr = 0; rr < 4; rr++) {
      int iv = __builtin_amdgcn_ds_bpermute((lanebase | (quad * 4 + rr)) << 2,
                                            __float_as_int(inv));
      float invr = __int_as_float(iv);
      size_t rowg = (size_t)(b * SEQ + qrow0 + rt * 16 + quad * 4 + rr);
#pragma unroll
      for (int dt = 0; dt < 4; dt++)
        O[rowg * D_MODEL + h * DHEAD + dt * 16 + l16] = f2b(o_acc[rt][dt][rr] * invr);
    }
  }
}

// ---------------------------------------------------------------------------
// out = LayerNorm(Ain + Bin)*g + bt. Bin bf16. Ain fp32 or bf16.
// ---------------------------------------------------------------------------
template <int AIN_BF16, int OUT_FP32, int OUT_BF16>
__global__ __launch_bounds__(256) void add_ln_kernel(
    const float* __restrict__ Ainf, const ushort* __restrict__ Ainb,
    const ushort* __restrict__ Binb,
    const float* __restrict__ g, const float* __restrict__ bt,
    float* __restrict__ outf, ushort* __restrict__ outb) {
  const int row = blockIdx.x, tid = threadIdx.x;
  __shared__ float red[4];
  float v[3];
  float s = 0.f;
#pragma unroll
  for (int u = 0; u < 3; u++) {
    int c = tid + u * 256;
    float a = AIN_BF16 ? b2f(Ainb[(size_t)row * 768 + c]) : Ainf[(size_t)row * 768 + c];
    v[u] = a + b2f(Binb[(size_t)row * 768 + c]);
    s += v[u];
  }
#pragma unroll
  for (int off = 32; off > 0; off >>= 1) s += __shfl_down(s, off);
  if ((tid & 63) == 0) red[tid >> 6] = s;
  __syncthreads();
  float mu = (red[0] + red[1] + red[2] + red[3]) * (1.f / 768.f);
  float s2 = 0.f;
#pragma unroll
  for (int u = 0; u < 3; u++) { float d = v[u] - mu; s2 += d * d; }
#pragma unroll
  for (int off = 32; off > 0; off >>= 1) s2 += __shfl_down(s2, off);
  __syncthreads();
  if ((tid & 63) == 0) red[tid >> 6] = s2;
  __syncthreads();
  float var = (red[0] + red[1] + red[2] + red[3]) * (1.f / 768.f);
  float inv = rsqrtf(var + 1e-12f);
#pragma unroll
  for (int u = 0; u < 3; u++) {
    int c = tid + u * 256;
    float r = g[c] * (v[u] - mu) * inv + bt[c];
    if (OUT_FP32) outf[(size_t)row * 768 + c] = r;
    if (OUT_BF16) outb[(size_t)row * 768 + c] = f2b(r);
  }
}

// ---------------------------------------------------------------------------
extern "C" void kernel_launch(void* const* d_in, const int* in_sizes, int n_in,
                              void* d_out, int out_size, void* d_ws, size_t ws_size,
                              hipStream_t stream) {
  const float* x    = (const float*)d_in[0];
  const float* mask = (const float*)d_in[1];
  const float* Pq   = (const float*)d_in[2];
  const float* Vq   = (const float*)d_in[3];
  const float* bq   = (const float*)d_in[4];
  const float* Pk   = (const float*)d_in[5];
  const float* Vk   = (const float*)d_in[6];
  const float* bk   = (const float*)d_in[7];
  const float* Pv   = (const float*)d_in[8];
  const float* Vv   = (const float*)d_in[9];
  const float* bv   = (const float*)d_in[10];
  const float* Uo   = (const float*)d_in[11];
  const float* Vo   = (const float*)d_in[12];
  const float* bo   = (const float*)d_in[13];
  const float* U1   = (const float*)d_in[14];
  const float* V1   = (const float*)d_in[15];
  const float* b1   = (const float*)d_in[16];
  const float* U2   = (const float*)d_in[17];
  const float* V2   = (const float*)d_in[18];
  const float* b2   = (const float*)d_in[19];
  const float* g1   = (const float*)d_in[20];
  const float* be1  = (const float*)d_in[21];
  const float* g2   = (const float*)d_in[22];
  const float* be2  = (const float*)d_in[23];

  // --- workspace carve (bytes, 256-aligned) ---
  char* w = (char*)d_ws;
  auto alloc = [&](size_t bytes) -> char* {
    char* p = w; w += (bytes + 255) & ~(size_t)255; return p;
  };
  ushort* xb     = (ushort*)alloc((size_t)BM * 768 * 2);
  ushort* Wqkvt  = (ushort*)alloc((size_t)2304 * 768 * 2);
  float*  ball   = (float*)alloc(2304 * 4);
  ushort* VoT    = (ushort*)alloc(768 * 384 * 2);   // Vo^T bf16 (A operand)
  ushort* Uob    = (ushort*)alloc(768 * 384 * 2);   // Uo bf16 (Bt operand)
  ushort* Wot    = (ushort*)alloc(768 * 768 * 2);   // Vo^T @ Uo^T = Wo^T
  ushort* U1t    = (ushort*)alloc(384 * 768 * 2);
  ushort* V1t    = (ushort*)alloc((size_t)3072 * 384 * 2);
  ushort* U2t    = (ushort*)alloc((size_t)384 * 3072 * 2);
  ushort* V2t    = (ushort*)alloc(768 * 384 * 2);
  ushort* Qb     = (ushort*)alloc((size_t)BM * 768 * 2);
  ushort* Kb     = (ushort*)alloc((size_t)BM * 768 * 2);
  ushort* Vtb    = (ushort*)alloc((size_t)768 * BM * 2);
  ushort* attnb  = (ushort*)alloc((size_t)BM * 768 * 2);
  ushort* mtb    = (ushort*)alloc((size_t)BM * 384 * 2);   // mid / t2
  ushort* y1b    = (ushort*)alloc((size_t)BM * 768 * 2);
  ushort* x1b    = (ushort*)alloc((size_t)BM * 768 * 2);
  float*  part   = (float*)alloc((size_t)4 * BM * 384 * 4);
  // aliases (dead-buffer reuse)
  ushort* hiddenb = Qb;             // Qb..attnb (50.3 MB) dead after y1 GEMM
  ushort* y2b     = y1b;            // y1b dead after LN1
  float*  outp    = (float*)d_out;

  // 1) conversions / weight prep
  f2b_kernel<<<(BM * 768) / 1024, 256, 0, stream>>>(x, xb, BM * 768);
  combine_qkv_kernel<<<dim3(2304, 3), 256, 0, stream>>>(Pq, Vq, Pk, Vk, Pv, Vv, Wqkvt);
  concat_bias_kernel<<<9, 256, 0, stream>>>(bq, bk, bv, ball);
  prep_weights_kernel<<<3456, 256, 0, stream>>>(U1, V1, U2, V2, Vo, Uo,
                                                U1t, V1t, U2t, V2t, VoT, Uob);
  // Wot[n][d] = sum_r Vo^T[n][r] * Uo[d][r]  (= Wo[d][n], the Bt operand for y1)
  gemm_n64_kernel<0><<<dim3(12, 6), 256, 0, stream>>>(VoT, Uob, nullptr, Wot, 768, 768, 384);

  // 2) fused QKV = x @ [Wq|Wk|Wv] + bias  (Q,K token-major; V transposed)
  gemm_mfma_kernel<3, 1, 0><<<dim3(18, 64), 256, 0, stream>>>(
      xb, Wqkvt, ball, Qb, Kb, Vtb, BM, 2304, 768);

  // 3) MFMA flash attention -> bf16 (B*M, 768)
  attn_mfma_kernel<<<dim3(8, 12, 8), 256, 0, stream>>>(Qb, Kb, Vtb, mask, attnb);

  // 4) attn out-projection: y1 = attn @ Wo + bo  (full-rank precombined)
  gemm_n64_kernel<1><<<dim3(12, 64), 256, 0, stream>>>(attnb, Wot, bo, y1b, BM, 768, 768);
  add_ln_kernel<0, 0, 1><<<BM, 256, 0, stream>>>(x, nullptr, y1b, g1, be1, nullptr, x1b);

  // 5) FFN (low rank) with fast GELU
  gemm_mfma_splitk_kernel<<<dim3(3, 64, 4), 256, 0, stream>>>(
      x1b, U1t, part, BM, 384, 768, 192);
  reduce_splitk_kernel<<<(BM * 384) / 1024, 256, 0, stream>>>(part, mtb, BM * 384, 4);
  gemm_mfma_kernel<1, 1, 1><<<dim3(24, 64), 256, 0, stream>>>(
      mtb, V1t, b1, hiddenb, nullptr, nullptr, BM, 3072, 384);
  gemm_mfma_splitk_kernel<<<dim3(3, 64, 4), 256, 0, stream>>>(
      hiddenb, U2t, part, BM, 384, 3072, 768);
  reduce_splitk_kernel<<<(BM * 384) / 1024, 256, 0, stream>>>(part, mtb, BM * 384, 4);
  gemm_n64_kernel<1><<<dim3(12, 64), 256, 0, stream>>>(mtb, V2t, b2, y2b, BM, 768, 384);

  // 6) residual + LN2 -> output (fp32)
  add_ln_kernel<1, 1, 0><<<BM, 256, 0, stream>>>(nullptr, x1b, y2b, g2, be2, outp, nullptr);
}